// Round 1
// baseline (1045.432 us; speedup 1.0000x reference)
//
#include <hip/hip_runtime.h>
#include <hip/hip_bf16.h>
#include <math.h>

// Problem constants
#define BB 2
#define CC 3
#define HH 512
#define WW 512
#define KK 8
#define GG 64
#define LL 4096
#define FDIM 128
#define PDIM 192   // C*K*K
#define MDIM 320   // PDIM + FDIM
#define DDIM 256
#define TOPK 16
#define RHID 128
#define SCALE (1.0f/16.0f)   // 1/(sqrt(256)*TEMP)

#define NQ 16      // queries per topk block
#define CHK 512    // key chunk
#define NCH (LL/CHK)
#define CAP 96     // candidate overflow capacity per query per chunk

// ---------------- kernel 1: copy image -> out, zero counts ----------------
__global__ void k_copy_init(const float* __restrict__ img, float* __restrict__ out,
                            int* __restrict__ count) {
    int i = blockIdx.x * blockDim.x + threadIdx.x;
    if (i < BB) count[i] = 0;
    int n4 = BB * CC * HH * WW / 4;
    const float4* s = (const float4*)img;
    float4* d = (float4*)out;
    for (int j = i; j < n4; j += gridDim.x * blockDim.x) d[j] = s[j];
}

// ---------------- kernel 2: build match tokens ----------------
__global__ void k_build(const float* __restrict__ img, const float* __restrict__ feat,
                        float* __restrict__ match) {
    int bl = blockIdx.x;              // 0..B*L-1
    int b = bl >> 12, l = bl & (LL - 1);
    int gy = l >> 6, gx = l & 63;
    int p = threadIdx.x;              // 0..319
    float v;
    if (p < PDIM) {
        int c = p >> 6, ky = (p >> 3) & 7, kx = p & 7;
        v = img[((b * CC + c) * HH + gy * 8 + ky) * WW + gx * 8 + kx];
    } else {
        v = feat[(b * FDIM + (p - PDIM)) * LL + l];
    }
    match[bl * MDIM + p] = v;
}

// ---------------- kernel 3: compact masked queries ----------------
__global__ void k_compact(const int* __restrict__ mask, int* __restrict__ qlist,
                          int* __restrict__ count) {
    int bl = blockIdx.x * blockDim.x + threadIdx.x;
    if (bl >= BB * LL) return;
    int b = bl >> 12, l = bl & (LL - 1);
    if (mask[bl] > 0) {
        int s = atomicAdd(&count[b], 1);
        qlist[b * LL + s] = l;
    }
}

// ---------------- kernel 4: token GEMM  out[t][col] = sum_m match[t][m]*W[m][col] ----
// col < cols0 -> W0, else W1 (for fused [Wq|Wk]); cols0+cols1 == 256 == blockDim.x
__global__ __launch_bounds__(256) void k_gemm_tok(const float* __restrict__ match,
        const float* __restrict__ W0, int cols0,
        const float* __restrict__ W1p, int cols1,
        float* __restrict__ out) {
    __shared__ float sm[32 * MDIM];
    int base = blockIdx.x * 32;
    int t = threadIdx.x;
    for (int i = t; i < 32 * MDIM; i += 256) sm[i] = match[base * MDIM + i];
    __syncthreads();
    const float* Wp;
    int ld, c;
    if (t < cols0) { Wp = W0; ld = cols0; c = t; }
    else           { Wp = W1p; ld = cols1; c = t - cols0; }
    float acc[32];
#pragma unroll
    for (int tt = 0; tt < 32; ++tt) acc[tt] = 0.f;
    for (int m = 0; m < MDIM; ++m) {
        float w = Wp[m * ld + c];
#pragma unroll
        for (int tt = 0; tt < 32; ++tt) acc[tt] += sm[tt * MDIM + m] * w;
    }
    int ncols = cols0 + cols1;
    for (int tt = 0; tt < 32; ++tt) out[(base + tt) * ncols + t] = acc[tt];
}

// ---------------- kernel 5: fused logits + top-16 ----------------
__device__ __forceinline__ void insert_topk(float* tv, int* ti, float v, int kidx) {
    // candidate beats slot j if v > tv[j] or (v==tv[j] && kidx < ti[j])  (lax.top_k ties -> lower idx)
    if (v > tv[TOPK - 1] || (v == tv[TOPK - 1] && kidx < ti[TOPK - 1])) {
        int pos = TOPK - 1;
        while (pos > 0 && (v > tv[pos - 1] || (v == tv[pos - 1] && kidx < ti[pos - 1]))) {
            tv[pos] = tv[pos - 1]; ti[pos] = ti[pos - 1]; --pos;
        }
        tv[pos] = v; ti[pos] = kidx;
    }
}

__global__ __launch_bounds__(256) void k_topk(const float* __restrict__ desc,
        const int* __restrict__ mask, const int* __restrict__ qlist,
        const int* __restrict__ count,
        float* __restrict__ tval, int* __restrict__ tidx) {
    int b = blockIdx.y;
    int cnt = count[b];
    int i0 = blockIdx.x * NQ;
    if (i0 >= cnt) return;
    int nq = min(NQ, cnt - i0);
    int t = threadIdx.x;

    __shared__ float sq[NQ * DDIM];          // 16 KB
    __shared__ float lc[NQ][CHK];            // 32 KB
    __shared__ float tv[NQ][TOPK];
    __shared__ int   ti[NQ][TOPK];
    __shared__ float cv[NQ][CAP];
    __shared__ int   ci[NQ][CAP];
    __shared__ int   nc[NQ];
    __shared__ int   sqs[NQ];

    if (t < NQ) {
        int slot = (t < nq) ? (i0 + t) : i0;
        sqs[t] = qlist[b * LL + slot];
        nc[t] = 0;
#pragma unroll
        for (int j = 0; j < TOPK; ++j) { tv[t][j] = -INFINITY; ti[t][j] = 0x7fffffff; }
    }
    __syncthreads();
    for (int i = t; i < NQ * DDIM; i += 256) {
        int qi = i >> 8, d = i & (DDIM - 1);
        sq[i] = desc[(b * LL + sqs[qi]) * DDIM + d];
    }
    __syncthreads();

    const float4* sq4 = (const float4*)sq;
    const float4* d4 = (const float4*)(desc + (size_t)b * LL * DDIM);
    const int* mb = mask + b * LL;

    for (int ch = 0; ch < NCH; ++ch) {
        int k0 = ch * CHK + t;
        int k1 = k0 + 256;
        float a0[NQ], a1[NQ];
#pragma unroll
        for (int qi = 0; qi < NQ; ++qi) { a0[qi] = 0.f; a1[qi] = 0.f; }
        for (int dd4 = 0; dd4 < DDIM / 4; ++dd4) {
            float4 x0 = d4[k0 * (DDIM / 4) + dd4];
            float4 x1 = d4[k1 * (DDIM / 4) + dd4];
#pragma unroll
            for (int qi = 0; qi < NQ; ++qi) {
                float4 s = sq4[qi * (DDIM / 4) + dd4];
                a0[qi] += s.x * x0.x + s.y * x0.y + s.z * x0.z + s.w * x0.w;
                a1[qi] += s.x * x1.x + s.y * x1.y + s.z * x1.z + s.w * x1.w;
            }
        }
        bool v0 = (mb[k0] == 0);
        bool v1 = (mb[k1] == 0);
#pragma unroll
        for (int qi = 0; qi < NQ; ++qi) {
            lc[qi][t]       = v0 ? a0[qi] * SCALE : -INFINITY;
            lc[qi][t + 256] = v1 ? a1[qi] * SCALE : -INFINITY;
        }
        __syncthreads();
        // parallel filter vs current threshold
        {
            int qi = t >> 4;
            int seg = (t & 15) * (CHK / 16);
            float thrv = tv[qi][TOPK - 1];
            int thri = ti[qi][TOPK - 1];
            for (int j = 0; j < CHK / 16; ++j) {
                float v = lc[qi][seg + j];
                if (v == -INFINITY) continue;
                int kidx = ch * CHK + seg + j;
                if (v > thrv || (v == thrv && kidx < thri)) {
                    int s = atomicAdd(&nc[qi], 1);
                    if (s < CAP) { cv[qi][s] = v; ci[qi][s] = kidx; }
                }
            }
        }
        __syncthreads();
        if (t < NQ) {
            int qi = t;
            int n = nc[qi];
            if (n > CAP) {
                // overflow (always true for chunk 0): full serial scan of this chunk
                for (int j = 0; j < CHK; ++j) {
                    float v = lc[qi][j];
                    if (v == -INFINITY) continue;
                    insert_topk(tv[qi], ti[qi], v, ch * CHK + j);
                }
            } else {
                for (int s = 0; s < n; ++s)
                    insert_topk(tv[qi], ti[qi], cv[qi][s], ci[qi][s]);
            }
            nc[qi] = 0;
        }
        __syncthreads();
    }

    if (t < NQ * TOPK) {
        int qi = t >> 4, j = t & 15;
        if (qi < nq) {
            int slot = b * LL + i0 + qi;
            tval[slot * TOPK + j] = tv[qi][j];
            tidx[slot * TOPK + j] = ti[qi][j];
        }
    }
}

// ---------------- kernel 6: MLP + softmax + blend + scatter ----------------
__global__ __launch_bounds__(128) void k_mlp(const float* __restrict__ match,
        const float* __restrict__ qkf,
        const float* __restrict__ tval, const int* __restrict__ tidx,
        const int* __restrict__ qlist, const int* __restrict__ count,
        const float* __restrict__ W1, const float* __restrict__ b1,
        const float* __restrict__ W2, const float* __restrict__ b2,
        float* __restrict__ out) {
    int b = blockIdx.y;
    int i = blockIdx.x;
    if (i >= count[b]) return;
    int q = qlist[b * LL + i];
    int slot = b * LL + i;
    int t = threadIdx.x;

    __shared__ float qfv[RHID];
    __shared__ float kfv[TOPK][RHID];
    __shared__ float tl[TOPK];
    __shared__ int   tix[TOPK];
    __shared__ float r0[TOPK], r1[TOPK];
    __shared__ float red[TOPK][2];
    __shared__ float wgt[TOPK];
    __shared__ float w2s[RHID];

    int gyq = q >> 6, gxq = q & 63;
    if (t < TOPK) {
        tl[t] = tval[slot * TOPK + t];
        int kidx = tidx[slot * TOPK + t];
        tix[t] = kidx;
        int gyk = kidx >> 6, gxk = kidx & 63;
        r0[t] = (float)(gyk - gyq) * (1.0f / GG);
        r1[t] = (float)(gxk - gxq) * (1.0f / GG);
    }
    qfv[t] = qkf[(b * LL + q) * 256 + t];
    w2s[t] = W2[t];
    __syncthreads();
    for (int i2 = t; i2 < TOPK * RHID; i2 += 128) {
        int kk = i2 >> 7, d = i2 & (RHID - 1);
        kfv[kk][d] = qkf[(b * LL + tix[kk]) * 256 + 128 + d];
    }
    __syncthreads();

    int h = t;
    float acc[TOPK];
#pragma unroll
    for (int kk = 0; kk < TOPK; ++kk) acc[kk] = 0.f;
    for (int j = 0; j < RHID; ++j) {
        float qv = qfv[j];
        float w1a = W1[j * RHID + h];
        float w1b = W1[(RHID + j) * RHID + h];
#pragma unroll
        for (int kk = 0; kk < TOPK; ++kk) {
            float kv = kfv[kk][j];
            acc[kk] += qv * kv * w1a + fabsf(qv - kv) * w1b;
        }
    }
    float wl  = W1[256 * RHID + h];
    float wr0 = W1[257 * RHID + h];
    float wr1 = W1[258 * RHID + h];
    float bb1 = b1[h];
    float w2v = w2s[h];
    float sc[TOPK];
#pragma unroll
    for (int kk = 0; kk < TOPK; ++kk) {
        float x = acc[kk] + tl[kk] * wl + r0[kk] * wr0 + r1[kk] * wr1 + bb1;
        float g = 0.5f * x * (1.0f + erff(x * 0.70710678118654752f));
        sc[kk] = g * w2v;
    }
    // reduce over 128 threads (2 waves)
    int lane = t & 63, wv = t >> 6;
#pragma unroll
    for (int kk = 0; kk < TOPK; ++kk) {
        float v = sc[kk];
        for (int off = 32; off > 0; off >>= 1) v += __shfl_down(v, off);
        if (lane == 0) red[kk][wv] = v;
    }
    __syncthreads();
    if (t < TOPK) {
        float score = red[t][0] + red[t][1] + b2[0];
        float refined = tl[t] + score;
        float m = refined;
        for (int off = 8; off > 0; off >>= 1) m = fmaxf(m, __shfl_xor(m, off, 16));
        float e = expf(refined - m);
        float s = e;
        for (int off = 8; off > 0; off >>= 1) s += __shfl_xor(s, off, 16);
        wgt[t] = e / s;
    }
    __syncthreads();
    // blend rgb candidates, scatter to output image
    for (int p = t; p < PDIM; p += 128) {
        float o = 0.f;
#pragma unroll
        for (int kk = 0; kk < TOPK; ++kk)
            o += wgt[kk] * match[(b * LL + tix[kk]) * MDIM + p];
        int c = p >> 6, ky = (p >> 3) & 7, kx = p & 7;
        out[((b * CC + c) * HH + gyq * 8 + ky) * WW + gxq * 8 + kx] = o;
    }
}

// ---------------- launch ----------------
extern "C" void kernel_launch(void* const* d_in, const int* in_sizes, int n_in,
                              void* d_out, int out_size, void* d_ws, size_t ws_size,
                              hipStream_t stream) {
    const float* image    = (const float*)d_in[0];
    const float* features = (const float*)d_in[1];
    const int*   tmask    = (const int*)d_in[2];
    const float* W_desc   = (const float*)d_in[3];
    const float* Wq       = (const float*)d_in[4];
    const float* Wk       = (const float*)d_in[5];
    const float* W1       = (const float*)d_in[6];
    const float* b1       = (const float*)d_in[7];
    const float* W2       = (const float*)d_in[8];
    const float* b2       = (const float*)d_in[9];
    float* out = (float*)d_out;

    float* ws    = (float*)d_ws;
    float* match = ws;                                    // B*L*320
    float* desc  = match + (size_t)BB * LL * MDIM;        // B*L*256
    float* qkf   = desc + (size_t)BB * LL * DDIM;         // B*L*256 ([qf|kf])
    float* tval  = qkf + (size_t)BB * LL * 256;           // B*L*16
    int*   tidx  = (int*)(tval + (size_t)BB * LL * TOPK); // B*L*16
    int*   qlist = tidx + (size_t)BB * LL * TOPK;         // B*L
    int*   count = qlist + BB * LL;                       // B

    k_copy_init<<<1024, 256, 0, stream>>>(image, out, count);
    k_build<<<BB * LL, MDIM, 0, stream>>>(image, features, match);
    k_compact<<<(BB * LL + 255) / 256, 256, 0, stream>>>(tmask, qlist, count);
    k_gemm_tok<<<BB * LL / 32, 256, 0, stream>>>(match, W_desc, 256, W_desc, 0, desc);
    k_gemm_tok<<<BB * LL / 32, 256, 0, stream>>>(match, Wq, 128, Wk, 128, qkf);
    k_topk<<<dim3(LL / NQ, BB), 256, 0, stream>>>(desc, tmask, qlist, count, tval, tidx);
    k_mlp<<<dim3(LL, BB), 128, 0, stream>>>(match, qkf, tval, tidx, qlist, count,
                                            W1, b1, W2, b2, out);
}

// Round 3
// 638.454 us; speedup vs baseline: 1.6374x; 1.6374x over previous
//
#include <hip/hip_runtime.h>
#include <hip/hip_bf16.h>
#include <math.h>

// Problem constants
#define BB 2
#define CC 3
#define HH 512
#define WW 512
#define GG 64
#define LL 4096
#define FDIM 128
#define PDIM 192   // C*K*K
#define MDIM 320   // PDIM + FDIM
#define DDIM 256
#define TOPK 16
#define RHID 128
#define SCALE (1.0f/16.0f)   // 1/(sqrt(256)*TEMP)

#define NQ2 8      // queries per topk block
#define CHK2 512   // key chunk (2 keys per thread, 256 threads)
#define TOKG 16    // tokens per gemm block

// ---------------- kernel 1: copy image -> out, zero counts ----------------
__global__ void k_copy_init(const float* __restrict__ img, float* __restrict__ out,
                            int* __restrict__ counts) {
    int i = blockIdx.x * blockDim.x + threadIdx.x;
    if (i < 2 * BB) counts[i] = 0;   // qcnt[B], kcnt[B]
    int n4 = BB * CC * HH * WW / 4;
    const float4* s = (const float4*)img;
    float4* d = (float4*)out;
    for (int j = i; j < n4; j += gridDim.x * blockDim.x) d[j] = s[j];
}

// ---------------- kernel 2: build match tokens ----------------
__global__ void k_build(const float* __restrict__ img, const float* __restrict__ feat,
                        float* __restrict__ match) {
    int bl = blockIdx.x;              // 0..B*L-1
    int b = bl >> 12, l = bl & (LL - 1);
    int gy = l >> 6, gx = l & 63;
    int p = threadIdx.x;              // 0..319
    float v;
    if (p < PDIM) {
        int c = p >> 6, ky = (p >> 3) & 7, kx = p & 7;
        v = img[((b * CC + c) * HH + gy * 8 + ky) * WW + gx * 8 + kx];
    } else {
        v = feat[(b * FDIM + (p - PDIM)) * LL + l];
    }
    match[(size_t)bl * MDIM + p] = v;
}

// ---------------- kernel 3: compact masked queries AND valid keys ----------------
__global__ void k_compact(const int* __restrict__ mask, int* __restrict__ qlist,
                          int* __restrict__ klist, int* __restrict__ counts) {
    int bl = blockIdx.x * blockDim.x + threadIdx.x;
    if (bl >= BB * LL) return;
    int b = bl >> 12, l = bl & (LL - 1);
    if (mask[bl] > 0) {
        int s = atomicAdd(&counts[b], 1);          // qcnt
        qlist[b * LL + s] = l;
    } else {
        int s = atomicAdd(&counts[BB + b], 1);     // kcnt
        klist[b * LL + s] = l;
    }
}

// ---------------- kernel 4: fused token GEMM (desc + [qf|kf]) ----------------
__global__ __launch_bounds__(256) void k_gemm2(const float* __restrict__ match,
        const float* __restrict__ Wd, const float* __restrict__ Wq,
        const float* __restrict__ Wk,
        float* __restrict__ desc, float* __restrict__ qkf) {
    __shared__ float sm[TOKG * MDIM];   // 20 KB
    int base = blockIdx.x * TOKG;
    int t = threadIdx.x;
    for (int i = t; i < TOKG * MDIM; i += 256) sm[i] = match[(size_t)base * MDIM + i];
    __syncthreads();
    const float4* sm4 = (const float4*)sm;
    const float* W1p = (t < 128) ? Wq : Wk;
    int c1 = t & 127;
    float acc0[TOKG], acc1[TOKG];
#pragma unroll
    for (int tt = 0; tt < TOKG; ++tt) { acc0[tt] = 0.f; acc1[tt] = 0.f; }
    for (int m = 0; m < MDIM; m += 4) {
        float w00 = Wd[(m+0)*DDIM + t], w01 = Wd[(m+1)*DDIM + t];
        float w02 = Wd[(m+2)*DDIM + t], w03 = Wd[(m+3)*DDIM + t];
        float w10 = W1p[(m+0)*RHID + c1], w11 = W1p[(m+1)*RHID + c1];
        float w12 = W1p[(m+2)*RHID + c1], w13 = W1p[(m+3)*RHID + c1];
        int mg = m >> 2;
#pragma unroll
        for (int tt = 0; tt < TOKG; ++tt) {
            float4 s = sm4[tt * (MDIM/4) + mg];
            acc0[tt] += s.x*w00 + s.y*w01 + s.z*w02 + s.w*w03;
            acc1[tt] += s.x*w10 + s.y*w11 + s.z*w12 + s.w*w13;
        }
    }
#pragma unroll
    for (int tt = 0; tt < TOKG; ++tt) {
        desc[(size_t)(base+tt)*DDIM + t] = acc0[tt];
        qkf [(size_t)(base+tt)*DDIM + t] = acc1[tt];
    }
}

// ---------------- kernel 5: gather valid-key descriptors densely ----------------
__global__ __launch_bounds__(256) void k_gatherk(const float* __restrict__ desc,
        const int* __restrict__ klist, const int* __restrict__ counts,
        float* __restrict__ kdesc) {
    int b = blockIdx.y;
    int vcnt = counts[BB + b];
    int t = threadIdx.x;
    int row = blockIdx.x * 4 + (t >> 6);
    if (row >= vcnt) return;
    int src = klist[b * LL + row];
    int lane = t & 63;
    const float4* s = (const float4*)(desc + ((size_t)b * LL + src) * DDIM);
    float4* d = (float4*)(kdesc + ((size_t)b * LL + row) * DDIM);
    d[lane] = s[lane];
}

// ---------------- kernel 6: fused logits + wave-register top-16 ----------------
__global__ __launch_bounds__(256) void k_topk2(const float* __restrict__ desc,
        const float* __restrict__ kdesc,
        const int* __restrict__ qlist, const int* __restrict__ klist,
        const int* __restrict__ counts,
        float* __restrict__ tval, int* __restrict__ tidx) {
    int b = blockIdx.y;
    int cnt  = counts[b];
    int vcnt = counts[BB + b];
    int i0 = blockIdx.x * NQ2;
    if (i0 >= cnt) return;
    int nq = min(NQ2, cnt - i0);
    int t = threadIdx.x;
    int lane = t & 63, w = t >> 6;

    __shared__ float sq[NQ2 * DDIM];    // 8 KB
    __shared__ float lc[NQ2][CHK2];     // 16 KB
    __shared__ int sqs[NQ2];

    if (t < NQ2) sqs[t] = qlist[b * LL + i0 + min(t, nq - 1)];
    __syncthreads();
    for (int i = t; i < NQ2 * DDIM; i += 256) {
        int qi = i >> 8, d = i & (DDIM - 1);
        sq[i] = desc[((size_t)b * LL + sqs[qi]) * DDIM + d];
    }
    __syncthreads();   // sq fully staged before any wave reads it (round-2 bug fix)

    // distributed top-16: wave w owns queries 2w, 2w+1; lane<16 holds sorted slot
    float tva = -INFINITY, tvb = -INFINITY;
    int   tia = 0x7fffffff, tib = 0x7fffffff;

    const float4* sq4 = (const float4*)sq;
    const float4* kd4 = (const float4*)(kdesc + (size_t)b * LL * DDIM);
    const int* klb = klist + b * LL;

    auto select_q = [&](float& tv, int& ti, int qi, int ch) {
#pragma unroll
        for (int j = 0; j < CHK2 / 64; ++j) {
            int s = j * 64 + lane;
            int gk = ch * CHK2 + s;
            float v = lc[qi][s];
            int kidx = (gk < vcnt) ? klb[gk] : 0x7fffffff;
            float thrv = __shfl(tv, 15);
            int   thri = __shfl(ti, 15);
            bool pass = (v > thrv) || (v == thrv && kidx < thri);
            unsigned long long m = __ballot(pass);
            while (m) {
                int src = __ffsll(m) - 1;
                float vv = __shfl(v, src);
                int   ii = __shfl(kidx, src);
                bool beat = (vv > tv) || (vv == tv && ii < ti);
                float pv = __shfl_up(tv, 1);
                int   pi = __shfl_up(ti, 1);
                bool beatp = (lane > 0) && ((vv > pv) || (vv == pv && ii < pi));
                if (lane < 16 && beat) { tv = beatp ? pv : vv; ti = beatp ? pi : ii; }
                m &= m - 1;
            }
        }
    };

    int nch = (vcnt + CHK2 - 1) / CHK2;
    for (int ch = 0; ch < nch; ++ch) {
        int s0 = ch * CHK2 + t;
        int s1 = s0 + 256;
        int r0 = min(s0, vcnt - 1);
        int r1 = min(s1, vcnt - 1);
        float a0[NQ2], a1[NQ2];
#pragma unroll
        for (int qi = 0; qi < NQ2; ++qi) { a0[qi] = 0.f; a1[qi] = 0.f; }
        const float4* k0p = kd4 + (size_t)r0 * (DDIM/4);
        const float4* k1p = kd4 + (size_t)r1 * (DDIM/4);
        for (int d4 = 0; d4 < DDIM/4; ++d4) {
            float4 x0 = k0p[d4];
            float4 x1 = k1p[d4];
#pragma unroll
            for (int qi = 0; qi < NQ2; ++qi) {
                float4 s = sq4[qi * (DDIM/4) + d4];
                a0[qi] += s.x*x0.x + s.y*x0.y + s.z*x0.z + s.w*x0.w;
                a1[qi] += s.x*x1.x + s.y*x1.y + s.z*x1.z + s.w*x1.w;
            }
        }
        __syncthreads();   // prev selection done reading lc
#pragma unroll
        for (int qi = 0; qi < NQ2; ++qi) {
            lc[qi][t]       = (s0 < vcnt) ? a0[qi] * SCALE : -INFINITY;
            lc[qi][t + 256] = (s1 < vcnt) ? a1[qi] * SCALE : -INFINITY;
        }
        __syncthreads();
        select_q(tva, tia, w * 2 + 0, ch);
        select_q(tvb, tib, w * 2 + 1, ch);
    }

    for (int qq = 0; qq < 2; ++qq) {
        int qi = w * 2 + qq;
        float tv = qq ? tvb : tva;
        int   ti = qq ? tib : tia;
        if (qi < nq && lane < 16) {
            tval[((size_t)b * LL + i0 + qi) * TOPK + lane] = tv;
            tidx[((size_t)b * LL + i0 + qi) * TOPK + lane] = ti;
        }
    }
}

// ---------------- kernel 7: MLP + softmax + blend + scatter ----------------
__global__ __launch_bounds__(128) void k_mlp(const float* __restrict__ match,
        const float* __restrict__ qkf,
        const float* __restrict__ tval, const int* __restrict__ tidx,
        const int* __restrict__ qlist, const int* __restrict__ counts,
        const float* __restrict__ W1, const float* __restrict__ b1,
        const float* __restrict__ W2, const float* __restrict__ b2,
        float* __restrict__ out) {
    int b = blockIdx.y;
    int i = blockIdx.x;
    if (i >= counts[b]) return;
    int q = qlist[b * LL + i];
    int slot = b * LL + i;
    int t = threadIdx.x;

    __shared__ float qfv[RHID];
    __shared__ float kfv[TOPK][RHID];
    __shared__ float tl[TOPK];
    __shared__ int   tix[TOPK];
    __shared__ float r0[TOPK], r1[TOPK];
    __shared__ float red[TOPK][2];
    __shared__ float wgt[TOPK];
    __shared__ float w2s[RHID];
    __shared__ float2 pkpa[RHID][TOPK + 1];   // padded to kill write conflicts

    int gyq = q >> 6, gxq = q & 63;
    if (t < TOPK) {
        tl[t] = tval[(size_t)slot * TOPK + t];
        int kidx = tidx[(size_t)slot * TOPK + t];
        if (kidx >= LL || kidx < 0) kidx = 0;   // crash-safety
        tix[t] = kidx;
        int gyk = kidx >> 6, gxk = kidx & 63;
        r0[t] = (float)(gyk - gyq) * (1.0f / GG);
        r1[t] = (float)(gxk - gxq) * (1.0f / GG);
    }
    qfv[t] = qkf[((size_t)b * LL + q) * DDIM + t];
    w2s[t] = W2[t];
    __syncthreads();
    for (int i2 = t; i2 < TOPK * RHID; i2 += 128) {
        int kk = i2 >> 7, d = i2 & (RHID - 1);
        kfv[kk][d] = qkf[((size_t)b * LL + tix[kk]) * DDIM + RHID + d];
    }
    __syncthreads();
    {
        float qv = qfv[t];   // j = t
#pragma unroll
        for (int kk = 0; kk < TOPK; ++kk) {
            float kv = kfv[kk][t];
            pkpa[t][kk] = make_float2(qv * kv, fabsf(qv - kv));
        }
    }
    __syncthreads();

    int h = t;
    float acc[TOPK];
#pragma unroll
    for (int kk = 0; kk < TOPK; ++kk) acc[kk] = 0.f;
    for (int j = 0; j < RHID; ++j) {
        float w1a = W1[j * RHID + h];
        float w1b = W1[(RHID + j) * RHID + h];
#pragma unroll
        for (int kk = 0; kk < TOPK; ++kk) {
            float2 p = pkpa[j][kk];
            acc[kk] += p.x * w1a + p.y * w1b;
        }
    }
    float wl  = W1[256 * RHID + h];
    float wr0 = W1[257 * RHID + h];
    float wr1 = W1[258 * RHID + h];
    float bb1 = b1[h];
    float w2v = w2s[h];
    float sc[TOPK];
#pragma unroll
    for (int kk = 0; kk < TOPK; ++kk) {
        float x = acc[kk] + tl[kk] * wl + r0[kk] * wr0 + r1[kk] * wr1 + bb1;
        float g = 0.5f * x * (1.0f + erff(x * 0.70710678118654752f));
        sc[kk] = g * w2v;
    }
    int lane = t & 63, wv = t >> 6;
#pragma unroll
    for (int kk = 0; kk < TOPK; ++kk) {
        float v = sc[kk];
        for (int off = 32; off > 0; off >>= 1) v += __shfl_down(v, off);
        if (lane == 0) red[kk][wv] = v;
    }
    __syncthreads();
    if (t < TOPK) {
        float score = red[t][0] + red[t][1] + b2[0];
        float refined = tl[t] + score;
        float m = refined;
        for (int off = 8; off > 0; off >>= 1) m = fmaxf(m, __shfl_xor(m, off, 16));
        float e = expf(refined - m);
        float s = e;
        for (int off = 8; off > 0; off >>= 1) s += __shfl_xor(s, off, 16);
        wgt[t] = e / s;
    }
    __syncthreads();
    for (int p = t; p < PDIM; p += 128) {
        float o = 0.f;
#pragma unroll
        for (int kk = 0; kk < TOPK; ++kk)
            o += wgt[kk] * match[((size_t)b * LL + tix[kk]) * MDIM + p];
        int c = p >> 6, ky = (p >> 3) & 7, kx = p & 7;
        out[((b * CC + c) * HH + gyq * 8 + ky) * WW + gxq * 8 + kx] = o;
    }
}

// ---------------- launch ----------------
extern "C" void kernel_launch(void* const* d_in, const int* in_sizes, int n_in,
                              void* d_out, int out_size, void* d_ws, size_t ws_size,
                              hipStream_t stream) {
    const float* image    = (const float*)d_in[0];
    const float* features = (const float*)d_in[1];
    const int*   tmask    = (const int*)d_in[2];
    const float* W_desc   = (const float*)d_in[3];
    const float* Wq       = (const float*)d_in[4];
    const float* Wk       = (const float*)d_in[5];
    const float* W1       = (const float*)d_in[6];
    const float* b1       = (const float*)d_in[7];
    const float* W2       = (const float*)d_in[8];
    const float* b2       = (const float*)d_in[9];
    float* out = (float*)d_out;

    float* ws    = (float*)d_ws;
    float* match = ws;                                     // B*L*320
    float* desc  = match + (size_t)BB * LL * MDIM;         // B*L*256
    float* qkf   = desc  + (size_t)BB * LL * DDIM;         // B*L*256
    float* kdesc = qkf   + (size_t)BB * LL * DDIM;         // B*L*256
    float* tval  = kdesc + (size_t)BB * LL * DDIM;         // B*L*16
    int*   tidx  = (int*)(tval + (size_t)BB * LL * TOPK);  // B*L*16
    int*   qlist = tidx + (size_t)BB * LL * TOPK;          // B*L
    int*   klist = qlist + BB * LL;                        // B*L
    int*   counts = klist + BB * LL;                       // 2*B

    k_copy_init<<<1024, 256, 0, stream>>>(image, out, counts);
    k_build<<<BB * LL, MDIM, 0, stream>>>(image, features, match);
    k_compact<<<(BB * LL + 255) / 256, 256, 0, stream>>>(tmask, qlist, klist, counts);
    k_gemm2<<<BB * LL / TOKG, 256, 0, stream>>>(match, W_desc, Wq, Wk, desc, qkf);
    k_gatherk<<<dim3(LL / 4, BB), 256, 0, stream>>>(desc, klist, counts, kdesc);
    k_topk2<<<dim3(LL / NQ2, BB), 256, 0, stream>>>(desc, kdesc, qlist, klist, counts,
                                                    tval, tidx);
    k_mlp<<<dim3(LL, BB), 128, 0, stream>>>(match, qkf, tval, tidx, qlist, counts,
                                            W1, b1, W2, b2, out);
}